// Round 5
// baseline (11196.283 us; speedup 1.0000x reference)
//
#include <hip/hip_runtime.h>
#include <hip/hip_bf16.h>

typedef __attribute__((ext_vector_type(8))) short short8;
typedef __attribute__((ext_vector_type(4))) float floatx4;

#define BB 2048   // batch
#define SS 24     // seq len
#define HH 1024   // hidden
#define VV 37     // vocab
#define EE 256    // embed
#define G4H 4096  // 4*H

__device__ __forceinline__ unsigned short f2bf(float f) {
    union { float f; unsigned u; } x; x.f = f;
    unsigned r = x.u + 0x7FFF + ((x.u >> 16) & 1);   // RNE
    return (unsigned short)(r >> 16);
}
__device__ __forceinline__ float bf2f(unsigned short s) {
    union { unsigned u; float f; } x; x.u = ((unsigned)s) << 16; return x.f;
}
__device__ __forceinline__ float sigm(float x) {
    x = fminf(fmaxf(x, -15.f), 15.f);
    return 1.f / (1.f + __expf(-x));
}
__device__ __forceinline__ float tanh_(float x) {
    x = fminf(fmaxf(x, -15.f), 15.f);
    float e = __expf(2.f * x);
    return (e - 1.f) / (e + 1.f);
}

// ---------------- setup kernels ----------------
__global__ __launch_bounds__(256)
void cvt_f2b_kernel(const float* __restrict__ s, unsigned short* __restrict__ d, int n4) {
    int i = blockIdx.x * 256 + threadIdx.x;
    if (i >= n4) return;
    float4 v = reinterpret_cast<const float4*>(s)[i];
    ushort4 o;
    o.x = f2bf(v.x); o.y = f2bf(v.y); o.z = f2bf(v.z); o.w = f2bf(v.w);
    reinterpret_cast<ushort4*>(d)[i] = o;
}

// fp32 -> bf16, gate-interleaved rows: out row 4u+g <- in row g*1024+u  (K=1024)
__global__ __launch_bounds__(256)
void cvt_perm_kernel(const float* __restrict__ s, unsigned short* __restrict__ d) {
    int i = blockIdx.x * 256 + threadIdx.x;     // 4096*256 float4 groups
    int r  = i >> 8;                            // out row
    int kk = i & 255;
    int u = r >> 2, g = r & 3;
    float4 v = reinterpret_cast<const float4*>(s)[(size_t)((g << 10) + u) * 256 + kk];
    ushort4 o;
    o.x = f2bf(v.x); o.y = f2bf(v.y); o.z = f2bf(v.z); o.w = f2bf(v.w);
    reinterpret_cast<ushort4*>(d)[(size_t)i] = o;
}

__global__ __launch_bounds__(256) void zero16_kernel(uint4* __restrict__ p) {
    uint4 z; z.x = 0; z.y = 0; z.z = 0; z.w = 0;
    p[(size_t)blockIdx.x * 256 + threadIdx.x] = z;
}

__global__ __launch_bounds__(256)
void tok_kernel(const int* __restrict__ src, const int* __restrict__ tgt, int* __restrict__ toks) {
    int idx = blockIdx.x * 256 + threadIdx.x;   // 2*24*2048
    int b  = idx & 2047;
    int st = idx >> 11;
    int tok;
    if (st < SS) tok = src[b * SS + st];
    else { int t = st - SS; tok = (t == 0) ? 1 : tgt[b * SS + (t - 1)]; }
    toks[idx] = tok;
}

// layer-1 bias sums, gate-interleaved: bsum[layer][4u+g] = b_ih[g*1024+u] + b_hh[...]
__global__ __launch_bounds__(256) void bias_sum_kernel(
        const float* e1i, const float* e1h, const float* d1i, const float* d1h,
        float* __restrict__ out) {
    int idx = blockIdx.x * 256 + threadIdx.x;   // 2*4096
    int layer = idx >> 12, jj = idx & 4095;
    int u = jj >> 2, g = jj & 3;
    int src_j = (g << 10) + u;
    const float* pi = layer ? d1i : e1i;
    const float* ph = layer ? d1h : e1h;
    out[idx] = pi[src_j] + ph[src_j];
}

// vocab gate tables: tab[t][v][u*4+g] = b_ih+b_hh + sum_k W_ih0[g*1024+u][k]*emb[v][k]  (fp32)
__global__ __launch_bounds__(256)
void xgtab_kernel(const float* __restrict__ eW, const float* __restrict__ ebi, const float* __restrict__ ebh,
                  const float* __restrict__ dW, const float* __restrict__ dbi, const float* __restrict__ dbh,
                  const float* __restrict__ emb, float* __restrict__ tab) {
    int idx = blockIdx.x * 256 + threadIdx.x;   // 2*37*4096
    if (idx >= 2 * VV * G4H) return;
    int rowg = idx & 4095;
    int v    = (idx >> 12) % VV;
    int ti   = idx / (VV * G4H);
    int u = rowg >> 2, g = rowg & 3;
    const float* W  = ti ? dW : eW;
    const float* bi = ti ? dbi : ebi;
    const float* bh = ti ? dbh : ebh;
    const float* er = emb + (size_t)v * EE;
    const float* wr = W + (size_t)((g << 10) + u) * EE;
    float s = bi[(g << 10) + u] + bh[(g << 10) + u];
#pragma unroll 8
    for (int k = 0; k < EE; ++k) s += wr[k] * er[k];
    tab[idx] = s;
}

// ---------------- fused LSTM step (no LDS / no barriers in K-loop) ----------------
struct StepArgs {
    const unsigned short* Wh;   // [4096][1024] gate-interleaved bf16
    const unsigned short* Sh;   // [2048][1024] bf16 state (B-operand seg0)
    const unsigned short* Wx;   // seg1 weights (null -> 1 segment)
    const unsigned short* Sx;   // seg1 state
    const float4* b4;           // per-unit (i,f,g,o) bias, null -> zeros
    const float4* xg;           // [37][1024] vocab gate table, null -> none
    const int* tok;             // [2048] tokens (with xg)
    float* c;                   // [1024][2048] fp32, unit-major
    unsigned short* hout;       // [2048][1024] bf16
    int valid;
};

// z=0 -> s0 (layer1 step d), z=1 -> s1 (layer0 step d+1), z=2 -> FC head of h1(d-1)
__global__ __launch_bounds__(256, 4)
void lstm_fused(StepArgs s0, StepArgs s1,
                const unsigned short* __restrict__ fch, int fct,
                const unsigned short* __restrict__ fcW, const float* __restrict__ fcb,
                float* __restrict__ out) {
    const int tid  = threadIdx.x;
    const int lane = tid & 63;
    const int wave = tid >> 6;

    if (blockIdx.z == 2) {      // ---- FC slice: logits for previous step's h1 ----
        if (!fch) return;
        const int row = (blockIdx.y * gridDim.x + blockIdx.x) * 4 + wave;   // 0..2047
        if (lane >= VV) return;
        const unsigned short* hrow = fch + (size_t)row * HH;
        const unsigned short* wrow = fcW + (size_t)lane * HH;
        float acc = fcb[lane];
#pragma unroll 4
        for (int k8 = 0; k8 < HH / 8; ++k8) {
            short8 hv = *reinterpret_cast<const short8*>(hrow + k8 * 8);
            short8 wv = *reinterpret_cast<const short8*>(wrow + k8 * 8);
#pragma unroll
            for (int uu = 0; uu < 8; ++uu)
                acc += bf2f((unsigned short)hv[uu]) * bf2f((unsigned short)wv[uu]);
        }
        out[(size_t)row * (SS * VV) + fct * VV + lane] = acc;
        return;
    }

    StepArgs S = (blockIdx.z == 0) ? s0 : s1;
    if (!S.valid) return;

    const int wm = wave >> 1, wn = wave & 1;
    const int m0 = blockIdx.x * 128;   // gate-row base
    const int n0 = blockIdx.y * 128;   // batch base

    floatx4 acc[4][4];
#pragma unroll
    for (int i = 0; i < 4; ++i)
#pragma unroll
        for (int j = 0; j < 4; ++j)
            acc[i][j] = (floatx4){0.f, 0.f, 0.f, 0.f};

    const int r16  = lane & 15;
    const int koff = (lane >> 4) << 3;

#pragma unroll 1
    for (int seg = 0; seg < 2; ++seg) {
        const unsigned short* W = seg ? S.Wx : S.Wh;
        const unsigned short* X = seg ? S.Sx : S.Sh;
        if (!W) break;
        const unsigned short* ap = W + (size_t)(m0 + wm * 64 + r16) * HH + koff;
        const unsigned short* bp = X + (size_t)(n0 + wn * 64 + r16) * HH + koff;
        short8 a0[4], b0[4], a1[4], b1[4];
#pragma unroll
        for (int i = 0; i < 4; ++i) {
            a0[i] = *reinterpret_cast<const short8*>(ap + i * 16 * HH);
            b0[i] = *reinterpret_cast<const short8*>(bp + i * 16 * HH);
        }
#pragma unroll 1
        for (int kc = 0; kc < HH; kc += 64) {
#pragma unroll
            for (int i = 0; i < 4; ++i) {
                a1[i] = *reinterpret_cast<const short8*>(ap + i * 16 * HH + kc + 32);
                b1[i] = *reinterpret_cast<const short8*>(bp + i * 16 * HH + kc + 32);
            }
#pragma unroll
            for (int i = 0; i < 4; ++i)
#pragma unroll
                for (int j = 0; j < 4; ++j)
                    acc[i][j] = __builtin_amdgcn_mfma_f32_16x16x32_bf16(a0[i], b0[j], acc[i][j], 0, 0, 0);
            if (kc + 64 < HH) {
#pragma unroll
                for (int i = 0; i < 4; ++i) {
                    a0[i] = *reinterpret_cast<const short8*>(ap + i * 16 * HH + kc + 64);
                    b0[i] = *reinterpret_cast<const short8*>(bp + i * 16 * HH + kc + 64);
                }
            }
#pragma unroll
            for (int i = 0; i < 4; ++i)
#pragma unroll
                for (int j = 0; j < 4; ++j)
                    acc[i][j] = __builtin_amdgcn_mfma_f32_16x16x32_bf16(a1[i], b1[j], acc[i][j], 0, 0, 0);
        }
    }

    // ---- epilogue: in-register cell; c unit-major (coalesced); h via LDS transpose ----
    __shared__ __align__(16) unsigned short hs[128][40];   // pad: row stride 80B (16B-mult)
    const int q = lane >> 4, r = lane & 15;
    const int ubase = (m0 >> 2) + wm * 16 + q;
    int bcol[4], tokv[4];
#pragma unroll
    for (int j = 0; j < 4; ++j) {
        bcol[j] = n0 + wn * 64 + j * 16 + r;
        tokv[j] = S.xg ? S.tok[bcol[j]] : 0;
    }
#pragma unroll
    for (int i = 0; i < 4; ++i) {
        const int unit = ubase + i * 4;
        float4 bv = S.b4 ? S.b4[unit] : make_float4(0.f, 0.f, 0.f, 0.f);
#pragma unroll
        for (int j = 0; j < 4; ++j) {
            float gx = acc[i][j][0] + bv.x;
            float gy = acc[i][j][1] + bv.y;
            float gz = acc[i][j][2] + bv.z;
            float gw = acc[i][j][3] + bv.w;
            if (S.xg) {
                float4 xv = S.xg[(size_t)tokv[j] * HH + unit];
                gx += xv.x; gy += xv.y; gz += xv.z; gw += xv.w;
            }
            float iv = sigm(gx), fv = sigm(gy), gv = tanh_(gz), ov = sigm(gw);
            const size_t ci = (size_t)unit * BB + bcol[j];
            float cn = fv * S.c[ci] + iv * gv;
            S.c[ci] = cn;
            hs[wn * 64 + j * 16 + r][wm * 16 + i * 4 + q] = f2bf(ov * tanh_(cn));
        }
    }
    __syncthreads();
    const int ub32 = m0 >> 2;
#pragma unroll
    for (int it = 0; it < 2; ++it) {
        const int idx = it * 256 + tid;          // 0..511
        const int bl = idx >> 2, u8 = (idx & 3) << 3;
        short8 v = *reinterpret_cast<const short8*>(&hs[bl][u8]);
        *reinterpret_cast<short8*>(S.hout + (size_t)(n0 + bl) * HH + ub32 + u8) = v;
    }
}

// standalone FC for the final timestep
__global__ __launch_bounds__(256)
void fc_step_kernel(const unsigned short* __restrict__ h1, const unsigned short* __restrict__ fcW,
                    const float* __restrict__ fcb, float* __restrict__ out, int t) {
    int b    = (blockIdx.x * 256 + threadIdx.x) >> 6;
    int lane = threadIdx.x & 63;
    if (lane >= VV) return;
    const unsigned short* hrow = h1 + (size_t)b * HH;
    const unsigned short* wrow = fcW + (size_t)lane * HH;
    float acc = fcb[lane];
#pragma unroll 4
    for (int k8 = 0; k8 < HH / 8; ++k8) {
        short8 hv = *reinterpret_cast<const short8*>(hrow + k8 * 8);
        short8 wv = *reinterpret_cast<const short8*>(wrow + k8 * 8);
#pragma unroll
        for (int uu = 0; uu < 8; ++uu)
            acc += bf2f((unsigned short)hv[uu]) * bf2f((unsigned short)wv[uu]);
    }
    out[(size_t)b * (SS * VV) + t * VV + lane] = acc;
}

extern "C" void kernel_launch(void* const* d_in, const int* in_sizes, int n_in,
                              void* d_out, int out_size, void* d_ws, size_t ws_size,
                              hipStream_t stream) {
    const int*   src    = (const int*)d_in[0];
    const int*   tgt    = (const int*)d_in[1];
    const float* emb    = (const float*)d_in[2];
    const float* eW_ih0 = (const float*)d_in[3];
    const float* eW_hh0 = (const float*)d_in[4];
    const float* eb_ih0 = (const float*)d_in[5];
    const float* eb_hh0 = (const float*)d_in[6];
    const float* eW_ih1 = (const float*)d_in[7];
    const float* eW_hh1 = (const float*)d_in[8];
    const float* eb_ih1 = (const float*)d_in[9];
    const float* eb_hh1 = (const float*)d_in[10];
    const float* dW_ih0 = (const float*)d_in[11];
    const float* dW_hh0 = (const float*)d_in[12];
    const float* db_ih0 = (const float*)d_in[13];
    const float* db_hh0 = (const float*)d_in[14];
    const float* dW_ih1 = (const float*)d_in[15];
    const float* dW_hh1 = (const float*)d_in[16];
    const float* db_ih1 = (const float*)d_in[17];
    const float* db_hh1 = (const float*)d_in[18];
    const float* fcW    = (const float*)d_in[19];
    const float* fcb    = (const float*)d_in[20];
    float* out = (float*)d_out;

    // ---- workspace ----
    char* w = (char*)d_ws;
    size_t off = 0;
    auto walloc = [&](size_t bytes) { void* p = w + off; off += (bytes + 255) & ~(size_t)255; return p; };
    // 6 gate-interleaved bf16 weights, all [4096][1024]
    unsigned short* bW[6];
    const float* srcW[6] = {eW_hh0, eW_ih1, eW_hh1, dW_hh0, dW_ih1, dW_hh1};
    for (int i = 0; i < 6; ++i) bW[i] = (unsigned short*)walloc((size_t)G4H * HH * 2);
    unsigned short* bfcW = (unsigned short*)walloc((size_t)VV * HH * 2);
    // zero region: h0a, h1a (bf16) + c0, c1 (fp32, unit-major) — contiguous 24 MiB
    unsigned short* h0a = (unsigned short*)walloc((size_t)BB * HH * 2);
    unsigned short* h1a = (unsigned short*)walloc((size_t)BB * HH * 2);
    float* c0 = (float*)walloc((size_t)HH * BB * 4);
    float* c1 = (float*)walloc((size_t)HH * BB * 4);
    unsigned short* h0b = (unsigned short*)walloc((size_t)BB * HH * 2);
    unsigned short* h1b = (unsigned short*)walloc((size_t)BB * HH * 2);
    float* bsum  = (float*)walloc((size_t)2 * G4H * 4);
    float* xgtab = (float*)walloc((size_t)2 * VV * G4H * 4);
    int*   toks  = (int*)walloc((size_t)2 * SS * BB * 4);

    unsigned short* h0buf[2] = {h0a, h0b};
    unsigned short* h1buf[2] = {h1a, h1b};

    // ---- setup ----
    for (int i = 0; i < 6; ++i)
        cvt_perm_kernel<<<4096, 256, 0, stream>>>(srcW[i], bW[i]);
    cvt_f2b_kernel<<<(VV * HH / 4 + 255) / 256, 256, 0, stream>>>(fcW, bfcW, VV * HH / 4);
    zero16_kernel<<<6144, 256, 0, stream>>>((uint4*)h0a);
    bias_sum_kernel<<<32, 256, 0, stream>>>(eb_ih1, eb_hh1, db_ih1, db_hh1, bsum);
    xgtab_kernel<<<(2 * VV * G4H + 255) / 256, 256, 0, stream>>>(
        eW_ih0, eb_ih0, eb_hh0, dW_ih0, db_ih0, db_hh0, emb, xgtab);
    tok_kernel<<<384, 256, 0, stream>>>(src, tgt, toks);

    const float4* b4e = (const float4*)bsum;            // enc layer1
    const float4* b4d = (const float4*)(bsum + G4H);    // dec layer1
    const float4* xg0 = (const float4*)xgtab;           // enc layer0
    const float4* xg1 = (const float4*)(xgtab + (size_t)VV * G4H);   // dec layer0

    StepArgs nil; nil.Wh = nullptr; nil.Sh = nullptr; nil.Wx = nullptr; nil.Sx = nullptr;
    nil.b4 = nullptr; nil.xg = nullptr; nil.tok = nullptr; nil.c = nullptr; nil.hout = nullptr; nil.valid = 0;

    // ---- prologue: layer0 step 0 ----
    {
        StepArgs p0 = { bW[0], h0buf[0], nullptr, nullptr, nullptr, xg0, toks, c0, h0buf[1], 1 };
        lstm_fused<<<dim3(32, 16, 1), 256, 0, stream>>>(p0, nil, nullptr, 0, bfcW, fcb, out);
    }

    // ---- main: dispatch d = layer1 step d + layer0 step d+1 + FC of step d-1 ----
    for (int d = 0; d < 48; ++d) {
        const unsigned short* h0cur = h0buf[1 ^ (d & 1)];
        unsigned short*       h0nxt = h0buf[d & 1];
        const unsigned short* h1in  = h1buf[d & 1];
        unsigned short*       h1out = h1buf[1 ^ (d & 1)];
        const bool l1enc = d < SS;
        const bool l0enc = (d + 1) < SS;

        StepArgs s0 = { l1enc ? bW[2] : bW[5], h1in, l1enc ? bW[1] : bW[4], h0cur,
                        l1enc ? b4e : b4d, nullptr, nullptr, c1, h1out, 1 };
        StepArgs s1 = nil;
        if (d < 47) {
            s1.Wh = l0enc ? bW[0] : bW[3]; s1.Sh = h0cur;
            s1.xg = l0enc ? xg0 : xg1; s1.tok = toks + (size_t)(d + 1) * BB;
            s1.c = c0; s1.hout = h0nxt; s1.valid = 1;
        }
        const unsigned short* fch = (d >= 25) ? h1buf[1 ^ ((d - 1) & 1)] : nullptr;
        lstm_fused<<<dim3(32, 16, 3), 256, 0, stream>>>(s0, s1, fch, d - 25, bfcW, fcb, out);
    }
    // final FC: t = 23 from h1 of dispatch d=47 (h1out = h1buf[0])
    fc_step_kernel<<<512, 256, 0, stream>>>(h1buf[0], bfcW, fcb, out, 23);
}

// Round 6
// 7262.131 us; speedup vs baseline: 1.5417x; 1.5417x over previous
//
#include <hip/hip_runtime.h>
#include <hip/hip_bf16.h>

typedef __attribute__((ext_vector_type(8))) short short8;
typedef __attribute__((ext_vector_type(4))) float floatx4;

#define BB 2048   // batch
#define SS 24     // seq len
#define HH 1024   // hidden
#define VV 37     // vocab
#define EE 256    // embed
#define G4H 4096  // 4*H

__device__ __forceinline__ unsigned short f2bf(float f) {
    union { float f; unsigned u; } x; x.f = f;
    unsigned r = x.u + 0x7FFF + ((x.u >> 16) & 1);   // RNE
    return (unsigned short)(r >> 16);
}
__device__ __forceinline__ float bf2f(unsigned short s) {
    union { unsigned u; float f; } x; x.u = ((unsigned)s) << 16; return x.f;
}
__device__ __forceinline__ float sigm(float x) {
    x = fminf(fmaxf(x, -15.f), 15.f);
    return 1.f / (1.f + __expf(-x));
}
__device__ __forceinline__ float tanh_(float x) {
    x = fminf(fmaxf(x, -15.f), 15.f);
    float e = __expf(2.f * x);
    return (e - 1.f) / (e + 1.f);
}

// async global->LDS DMA, 16B/lane; LDS dest = wave-uniform base + lane*16 [m97/m104]
typedef const __attribute__((address_space(1))) void* gas_t;
typedef __attribute__((address_space(3))) void* las_t;
__device__ __forceinline__ void gl_lds16(const void* g, void* l) {
    __builtin_amdgcn_global_load_lds((gas_t)g, (las_t)l, 16, 0, 0);
}

// ---------------- setup kernels ----------------
__global__ __launch_bounds__(256)
void cvt_f2b_kernel(const float* __restrict__ s, unsigned short* __restrict__ d, int n4) {
    int i = blockIdx.x * 256 + threadIdx.x;
    if (i >= n4) return;
    float4 v = reinterpret_cast<const float4*>(s)[i];
    ushort4 o;
    o.x = f2bf(v.x); o.y = f2bf(v.y); o.z = f2bf(v.z); o.w = f2bf(v.w);
    reinterpret_cast<ushort4*>(d)[i] = o;
}

// fp32 -> bf16, gate-interleaved rows: out row 4u+g <- in row g*1024+u  (K=1024)
__global__ __launch_bounds__(256)
void cvt_perm_kernel(const float* __restrict__ s, unsigned short* __restrict__ d) {
    int i = blockIdx.x * 256 + threadIdx.x;     // 4096*256 float4 groups
    int r  = i >> 8;                            // out row
    int kk = i & 255;
    int u = r >> 2, g = r & 3;
    float4 v = reinterpret_cast<const float4*>(s)[(size_t)((g << 10) + u) * 256 + kk];
    ushort4 o;
    o.x = f2bf(v.x); o.y = f2bf(v.y); o.z = f2bf(v.z); o.w = f2bf(v.w);
    reinterpret_cast<ushort4*>(d)[(size_t)i] = o;
}

__global__ __launch_bounds__(256) void zero16_kernel(uint4* __restrict__ p) {
    uint4 z; z.x = 0; z.y = 0; z.z = 0; z.w = 0;
    p[(size_t)blockIdx.x * 256 + threadIdx.x] = z;
}

__global__ __launch_bounds__(256)
void tok_kernel(const int* __restrict__ src, const int* __restrict__ tgt, int* __restrict__ toks) {
    int idx = blockIdx.x * 256 + threadIdx.x;   // 2*24*2048
    int b  = idx & 2047;
    int st = idx >> 11;
    int tok;
    if (st < SS) tok = src[b * SS + st];
    else { int t = st - SS; tok = (t == 0) ? 1 : tgt[b * SS + (t - 1)]; }
    toks[idx] = tok;
}

// layer-1 bias sums, gate-interleaved
__global__ __launch_bounds__(256) void bias_sum_kernel(
        const float* e1i, const float* e1h, const float* d1i, const float* d1h,
        float* __restrict__ out) {
    int idx = blockIdx.x * 256 + threadIdx.x;   // 2*4096
    int layer = idx >> 12, jj = idx & 4095;
    int u = jj >> 2, g = jj & 3;
    int src_j = (g << 10) + u;
    const float* pi = layer ? d1i : e1i;
    const float* ph = layer ? d1h : e1h;
    out[idx] = pi[src_j] + ph[src_j];
}

// vocab gate tables: tab[t][v][4u+g] = b_ih+b_hh + sum_k W_ih0[g*1024+u][k]*emb[v][k]
__global__ __launch_bounds__(256)
void xgtab_kernel(const float* __restrict__ eW, const float* __restrict__ ebi, const float* __restrict__ ebh,
                  const float* __restrict__ dW, const float* __restrict__ dbi, const float* __restrict__ dbh,
                  const float* __restrict__ emb, float* __restrict__ tab) {
    int idx = blockIdx.x * 256 + threadIdx.x;   // 2*37*4096
    if (idx >= 2 * VV * G4H) return;
    int rowg = idx & 4095;
    int v    = (idx >> 12) % VV;
    int ti   = idx / (VV * G4H);
    int u = rowg >> 2, g = rowg & 3;
    const float* W  = ti ? dW : eW;
    const float* bi = ti ? dbi : ebi;
    const float* bh = ti ? dbh : ebh;
    const float* er = emb + (size_t)v * EE;
    const float* wr = W + (size_t)((g << 10) + u) * EE;
    float s = bi[(g << 10) + u] + bh[(g << 10) + u];
#pragma unroll 8
    for (int k = 0; k < EE; ++k) s += wr[k] * er[k];
    tab[idx] = s;
}

// ---------------- merged fused LSTM step ----------------
struct StepArgs {
    const unsigned short* Wh;   // seg0 weights [4096][1024] gate-interleaved bf16
    const unsigned short* Sh;   // seg0 state   [2048][1024] bf16 batch-major
    const unsigned short* Wx;   // seg1 weights (null -> single segment)
    const unsigned short* Sx;   // seg1 state
    const float4* b4;           // [1024] per-unit (i,f,g,o) bias, or null
    const float4* xg;           // [37][1024] float4 vocab gate table, or null
    const int* tok;             // [2048]
    float* c;                   // [2048][1024] fp32 batch-major
    unsigned short* hout;       // [2048][1024] bf16
    int valid;
};

// grid (96, 16): x = z*32+m  ->  linear_block_id % 8 == m % 8  (XCD weight locality)
// z=0 -> s0 (layer1 step d), z=1 -> s1 (layer0 step d+1), z=2 -> FC of h1(d-1)
__global__ __launch_bounds__(256, 4)
void lstm_fused(StepArgs s0, StepArgs s1,
                const unsigned short* __restrict__ fch, int fct,
                const unsigned short* __restrict__ fcW, const float* __restrict__ fcb,
                float* __restrict__ out) {
    const int tid  = threadIdx.x;
    const int lane = tid & 63;
    const int wave = tid >> 6;
    const int zx = blockIdx.x;          // 0..95
    const int z  = zx >> 5, m = zx & 31;
    const int n  = blockIdx.y;

    if (z == 2) {      // ---- FC slice: logits for previous step's h1 ----
        if (!fch) return;
        const int row = (n * 32 + m) * 4 + wave;    // 0..2047
        if (lane >= VV) return;
        const unsigned short* hrow = fch + (size_t)row * HH;
        const unsigned short* wrow = fcW + (size_t)lane * HH;
        float acc = fcb[lane];
#pragma unroll 4
        for (int k8 = 0; k8 < HH / 8; ++k8) {
            short8 hv = *reinterpret_cast<const short8*>(hrow + k8 * 8);
            short8 wv = *reinterpret_cast<const short8*>(wrow + k8 * 8);
#pragma unroll
            for (int uu = 0; uu < 8; ++uu)
                acc += bf2f((unsigned short)hv[uu]) * bf2f((unsigned short)wv[uu]);
        }
        out[(size_t)row * (SS * VV) + fct * VV + lane] = acc;
        return;
    }

    StepArgs S = (z == 0) ? s0 : s1;
    if (!S.valid) return;

    __shared__ __align__(16) unsigned char smem[32768];
    unsigned short* As = (unsigned short*)smem;             // 16 KB: 16 subtiles x 1 KB
    unsigned short* Bs = (unsigned short*)(smem + 16384);   // 16 KB
    float* Gs = (float*)smem;                               // 32 KB epilogue reuse (128x64 fp32)

    const int wm = wave >> 1, wn = wave & 1;
    const int m0 = m * 128;    // gate-row base
    const int n0 = n * 128;    // batch base

    floatx4 acc[4][4];
#pragma unroll
    for (int i = 0; i < 4; ++i)
#pragma unroll
        for (int j = 0; j < 4; ++j)
            acc[i][j] = (floatx4){0.f, 0.f, 0.f, 0.f};

    const int r16  = lane & 15;
    const int koff = (lane >> 4) << 3;
    const int t0 = wave, t1 = wave + 4;

#pragma unroll 1
    for (int seg = 0; seg < 2; ++seg) {
        const unsigned short* A = seg ? S.Wx : S.Wh;
        const unsigned short* B = seg ? S.Sx : S.Sh;
        if (!A) break;
        const size_t a0 = (size_t)(m0 + t0 * 16 + r16) * HH + koff;
        const size_t a1 = (size_t)(m0 + t1 * 16 + r16) * HH + koff;
        const size_t b0 = (size_t)(n0 + t0 * 16 + r16) * HH + koff;
        const size_t b1 = (size_t)(n0 + t1 * 16 + r16) * HH + koff;
        for (int kc = 0; kc < HH; kc += 64) {
            gl_lds16(A + a0 + kc,      As + ((t0 * 2 + 0) << 9));
            gl_lds16(A + a0 + kc + 32, As + ((t0 * 2 + 1) << 9));
            gl_lds16(A + a1 + kc,      As + ((t1 * 2 + 0) << 9));
            gl_lds16(A + a1 + kc + 32, As + ((t1 * 2 + 1) << 9));
            gl_lds16(B + b0 + kc,      Bs + ((t0 * 2 + 0) << 9));
            gl_lds16(B + b0 + kc + 32, Bs + ((t0 * 2 + 1) << 9));
            gl_lds16(B + b1 + kc,      Bs + ((t1 * 2 + 0) << 9));
            gl_lds16(B + b1 + kc + 32, Bs + ((t1 * 2 + 1) << 9));
            __syncthreads();
#pragma unroll
            for (int h = 0; h < 2; ++h) {
                short8 af[4], bfr[4];
#pragma unroll
                for (int i = 0; i < 4; ++i) {
                    af[i]  = *reinterpret_cast<const short8*>(As + ((((wm * 4 + i) * 2 + h) << 9) + (lane << 3)));
                    bfr[i] = *reinterpret_cast<const short8*>(Bs + ((((wn * 4 + i) * 2 + h) << 9) + (lane << 3)));
                }
#pragma unroll
                for (int i = 0; i < 4; ++i)
#pragma unroll
                    for (int j = 0; j < 4; ++j)
                        acc[i][j] = __builtin_amdgcn_mfma_f32_16x16x32_bf16(af[i], bfr[j], acc[i][j], 0, 0, 0);
            }
            __syncthreads();
        }
    }

    // ---- two-pass epilogue: gate-cols 64 per pass through 32 KB Gs ----
    // C/D layout: gate-col = m0 + wm*64 + i*16 + q*4 + p, batch = n0 + wn*64 + j*16 + r  [m89]
    const int q = lane >> 4, r = lane & 15;
    const int u    = tid & 15;        // unit within pass (16 units)
    const int rgrp = tid >> 4;        // 16 groups x 8 batch rows
#pragma unroll
    for (int gp = 0; gp < 2; ++gp) {
        if (wm == gp) {
#pragma unroll
            for (int j = 0; j < 4; ++j)
#pragma unroll
                for (int i = 0; i < 4; ++i)
#pragma unroll
                    for (int p = 0; p < 4; ++p)
                        Gs[(wn * 64 + j * 16 + r) * 64 + (i * 16 + q * 4 + p)] = acc[i][j][p];
        }
        __syncthreads();
        const int unit = (m0 >> 2) + gp * 16 + u;
        float4 bv = S.b4 ? S.b4[unit] : make_float4(0.f, 0.f, 0.f, 0.f);
#pragma unroll
        for (int rr = 0; rr < 8; ++rr) {
            const int row = rgrp * 8 + rr;                  // batch-local
            float4 g4 = *reinterpret_cast<const float4*>(Gs + row * 64 + u * 4);
            float gx = g4.x + bv.x, gy = g4.y + bv.y, gz = g4.z + bv.z, gw = g4.w + bv.w;
            if (S.xg) {
                float4 xv = S.xg[(size_t)S.tok[n0 + row] * HH + unit];
                gx += xv.x; gy += xv.y; gz += xv.z; gw += xv.w;
            }
            float iv = sigm(gx), fv = sigm(gy), gv = tanh_(gz), ov = sigm(gw);
            const size_t ci = (size_t)(n0 + row) * HH + unit;
            float cn = fv * S.c[ci] + iv * gv;
            S.c[ci] = cn;
            S.hout[ci] = f2bf(ov * tanh_(cn));
        }
        __syncthreads();
    }
}

// standalone FC for the final timestep
__global__ __launch_bounds__(256)
void fc_step_kernel(const unsigned short* __restrict__ h1, const unsigned short* __restrict__ fcW,
                    const float* __restrict__ fcb, float* __restrict__ out, int t) {
    int b    = (blockIdx.x * 256 + threadIdx.x) >> 6;
    int lane = threadIdx.x & 63;
    if (lane >= VV) return;
    const unsigned short* hrow = h1 + (size_t)b * HH;
    const unsigned short* wrow = fcW + (size_t)lane * HH;
    float acc = fcb[lane];
#pragma unroll 4
    for (int k8 = 0; k8 < HH / 8; ++k8) {
        short8 hv = *reinterpret_cast<const short8*>(hrow + k8 * 8);
        short8 wv = *reinterpret_cast<const short8*>(wrow + k8 * 8);
#pragma unroll
        for (int uu = 0; uu < 8; ++uu)
            acc += bf2f((unsigned short)hv[uu]) * bf2f((unsigned short)wv[uu]);
    }
    out[(size_t)b * (SS * VV) + t * VV + lane] = acc;
}

extern "C" void kernel_launch(void* const* d_in, const int* in_sizes, int n_in,
                              void* d_out, int out_size, void* d_ws, size_t ws_size,
                              hipStream_t stream) {
    const int*   src    = (const int*)d_in[0];
    const int*   tgt    = (const int*)d_in[1];
    const float* emb    = (const float*)d_in[2];
    const float* eW_ih0 = (const float*)d_in[3];
    const float* eW_hh0 = (const float*)d_in[4];
    const float* eb_ih0 = (const float*)d_in[5];
    const float* eb_hh0 = (const float*)d_in[6];
    const float* eW_ih1 = (const float*)d_in[7];
    const float* eW_hh1 = (const float*)d_in[8];
    const float* eb_ih1 = (const float*)d_in[9];
    const float* eb_hh1 = (const float*)d_in[10];
    const float* dW_ih0 = (const float*)d_in[11];
    const float* dW_hh0 = (const float*)d_in[12];
    const float* db_ih0 = (const float*)d_in[13];
    const float* db_hh0 = (const float*)d_in[14];
    const float* dW_ih1 = (const float*)d_in[15];
    const float* dW_hh1 = (const float*)d_in[16];
    const float* db_ih1 = (const float*)d_in[17];
    const float* db_hh1 = (const float*)d_in[18];
    const float* fcW    = (const float*)d_in[19];
    const float* fcb    = (const float*)d_in[20];
    float* out = (float*)d_out;

    // ---- workspace ----
    char* w = (char*)d_ws;
    size_t off = 0;
    auto walloc = [&](size_t bytes) { void* p = w + off; off += (bytes + 255) & ~(size_t)255; return p; };
    unsigned short* bW[6];
    const float* srcW[6] = {eW_hh0, eW_ih1, eW_hh1, dW_hh0, dW_ih1, dW_hh1};
    for (int i = 0; i < 6; ++i) bW[i] = (unsigned short*)walloc((size_t)G4H * HH * 2);
    unsigned short* bfcW = (unsigned short*)walloc((size_t)VV * HH * 2);
    // zero region: h0a, h1a (bf16) + c0, c1 (fp32, batch-major) — contiguous 24 MiB
    unsigned short* h0a = (unsigned short*)walloc((size_t)BB * HH * 2);
    unsigned short* h1a = (unsigned short*)walloc((size_t)BB * HH * 2);
    float* c0 = (float*)walloc((size_t)BB * HH * 4);
    float* c1 = (float*)walloc((size_t)BB * HH * 4);
    unsigned short* h0b = (unsigned short*)walloc((size_t)BB * HH * 2);
    unsigned short* h1b = (unsigned short*)walloc((size_t)BB * HH * 2);
    float* bsum  = (float*)walloc((size_t)2 * G4H * 4);
    float* xgtab = (float*)walloc((size_t)2 * VV * G4H * 4);
    int*   toks  = (int*)walloc((size_t)2 * SS * BB * 4);

    unsigned short* h0buf[2] = {h0a, h0b};
    unsigned short* h1buf[2] = {h1a, h1b};

    // ---- setup ----
    for (int i = 0; i < 6; ++i)
        cvt_perm_kernel<<<4096, 256, 0, stream>>>(srcW[i], bW[i]);
    cvt_f2b_kernel<<<(VV * HH / 4 + 255) / 256, 256, 0, stream>>>(fcW, bfcW, VV * HH / 4);
    zero16_kernel<<<6144, 256, 0, stream>>>((uint4*)h0a);
    bias_sum_kernel<<<32, 256, 0, stream>>>(eb_ih1, eb_hh1, db_ih1, db_hh1, bsum);
    xgtab_kernel<<<(2 * VV * G4H + 255) / 256, 256, 0, stream>>>(
        eW_ih0, eb_ih0, eb_hh0, dW_ih0, db_ih0, db_hh0, emb, xgtab);
    tok_kernel<<<384, 256, 0, stream>>>(src, tgt, toks);

    const float4* b4e = (const float4*)bsum;            // enc layer1 bias
    const float4* b4d = (const float4*)(bsum + G4H);    // dec layer1 bias
    const float4* xg0 = (const float4*)xgtab;           // enc layer0 table
    const float4* xg1 = (const float4*)(xgtab + (size_t)VV * G4H);   // dec layer0 table

    StepArgs nil; nil.Wh = nullptr; nil.Sh = nullptr; nil.Wx = nullptr; nil.Sx = nullptr;
    nil.b4 = nullptr; nil.xg = nullptr; nil.tok = nullptr; nil.c = nullptr; nil.hout = nullptr; nil.valid = 0;

    dim3 grid(96, 16);

    // ---- prologue: layer0 step 0 only ----
    {
        StepArgs p1 = { bW[0], h0buf[0], nullptr, nullptr, nullptr, xg0, toks, c0, h0buf[1], 1 };
        lstm_fused<<<grid, 256, 0, stream>>>(nil, p1, nullptr, 0, bfcW, fcb, out);
    }

    // ---- main: dispatch d = layer1 step d + layer0 step d+1 + FC of step d-1 ----
    for (int d = 0; d < 48; ++d) {
        const unsigned short* h0cur = h0buf[1 ^ (d & 1)];
        unsigned short*       h0nxt = h0buf[d & 1];
        const unsigned short* h1in  = h1buf[d & 1];
        unsigned short*       h1out = h1buf[1 ^ (d & 1)];
        const bool l1enc = d < SS;
        const bool l0enc = (d + 1) < SS;

        StepArgs s0 = { l1enc ? bW[2] : bW[5], h1in, l1enc ? bW[1] : bW[4], h0cur,
                        l1enc ? b4e : b4d, nullptr, nullptr, c1, h1out, 1 };
        StepArgs s1 = nil;
        if (d < 47) {
            s1.Wh = l0enc ? bW[0] : bW[3]; s1.Sh = h0cur;
            s1.xg = l0enc ? xg0 : xg1; s1.tok = toks + (size_t)(d + 1) * BB;
            s1.c = c0; s1.hout = h0nxt; s1.valid = 1;
        }
        const unsigned short* fch = (d >= 25) ? h1buf[1 ^ ((d - 1) & 1)] : nullptr;
        lstm_fused<<<grid, 256, 0, stream>>>(s0, s1, fch, d - 25, bfcW, fcb, out);
    }
    // final FC: t = 23 from h1 of dispatch d=47 (h1out = h1buf[0])
    fc_step_kernel<<<512, 256, 0, stream>>>(h1buf[0], bfcW, fcb, out, 23);
}

// Round 7
// 7124.825 us; speedup vs baseline: 1.5714x; 1.0193x over previous
//
#include <hip/hip_runtime.h>
#include <hip/hip_bf16.h>

typedef __attribute__((ext_vector_type(8))) short short8;
typedef __attribute__((ext_vector_type(4))) float floatx4;

#define BB 2048   // batch
#define SS 24     // seq len
#define HH 1024   // hidden
#define VV 37     // vocab
#define EE 256    // embed
#define G4H 4096  // 4*H

__device__ __forceinline__ unsigned short f2bf(float f) {
    union { float f; unsigned u; } x; x.f = f;
    unsigned r = x.u + 0x7FFF + ((x.u >> 16) & 1);   // RNE
    return (unsigned short)(r >> 16);
}
__device__ __forceinline__ float bf2f(unsigned short s) {
    union { unsigned u; float f; } x; x.u = ((unsigned)s) << 16; return x.f;
}
__device__ __forceinline__ unsigned short f2h(float f) {   // fp32 -> fp16 RNE
    _Float16 h = (_Float16)f;
    union { _Float16 h; unsigned short u; } x; x.h = h; return x.u;
}
__device__ __forceinline__ float h2f(unsigned short s) {
    union { _Float16 h; unsigned short u; } x; x.u = s; return (float)x.h;
}
__device__ __forceinline__ float sigm(float x) {
    x = fminf(fmaxf(x, -15.f), 15.f);
    return 1.f / (1.f + __expf(-x));
}
__device__ __forceinline__ float tanh_(float x) {
    x = fminf(fmaxf(x, -15.f), 15.f);
    float e = __expf(2.f * x);
    return (e - 1.f) / (e + 1.f);
}

// async global->LDS DMA, 16B/lane; LDS dest = wave-uniform base + lane*16 [m97/m104]
typedef const __attribute__((address_space(1))) void* gas_t;
typedef __attribute__((address_space(3))) void* las_t;
__device__ __forceinline__ void gl_lds16(const void* g, void* l) {
    __builtin_amdgcn_global_load_lds((gas_t)g, (las_t)l, 16, 0, 0);
}

// ---------------- setup kernels ----------------
__global__ __launch_bounds__(256)
void cvt_f2b_kernel(const float* __restrict__ s, unsigned short* __restrict__ d, int n4) {
    int i = blockIdx.x * 256 + threadIdx.x;
    if (i >= n4) return;
    float4 v = reinterpret_cast<const float4*>(s)[i];
    ushort4 o;
    o.x = f2bf(v.x); o.y = f2bf(v.y); o.z = f2bf(v.z); o.w = f2bf(v.w);
    reinterpret_cast<ushort4*>(d)[i] = o;
}

// fp32 -> bf16, gate-interleaved rows: out row 4u+g <- in row g*1024+u
__global__ __launch_bounds__(256)
void cvt_perm_kernel(const float* __restrict__ s, unsigned short* __restrict__ d, int kqshift) {
    int i = blockIdx.x * 256 + threadIdx.x;     // 4096 * K/4 float4 groups
    int kq = 1 << kqshift;
    int r  = i >> kqshift;
    int kk = i & (kq - 1);
    int u = r >> 2, g = r & 3;
    float4 v = reinterpret_cast<const float4*>(s)[(size_t)((g << 10) + u) * kq + kk];
    ushort4 o;
    o.x = f2bf(v.x); o.y = f2bf(v.y); o.z = f2bf(v.z); o.w = f2bf(v.w);
    reinterpret_cast<ushort4*>(d)[(size_t)i] = o;
}

__global__ __launch_bounds__(256) void zero16_kernel(uint4* __restrict__ p) {
    uint4 z; z.x = 0; z.y = 0; z.z = 0; z.w = 0;
    p[(size_t)blockIdx.x * 256 + threadIdx.x] = z;
}

__global__ __launch_bounds__(256)
void tok_kernel(const int* __restrict__ src, const int* __restrict__ tgt, int* __restrict__ toks) {
    int idx = blockIdx.x * 256 + threadIdx.x;   // 2*24*2048
    int b  = idx & 2047;
    int st = idx >> 11;
    int tok;
    if (st < SS) tok = src[b * SS + st];
    else { int t = st - SS; tok = (t == 0) ? 1 : tgt[b * SS + (t - 1)]; }
    toks[idx] = tok;
}

// per-layer bias sums (4 layers), gate-interleaved
__global__ __launch_bounds__(256) void bias_sum_kernel(
        const float* e0i, const float* e0h, const float* e1i, const float* e1h,
        const float* d0i, const float* d0h, const float* d1i, const float* d1h,
        float* __restrict__ out) {
    int idx = blockIdx.x * 256 + threadIdx.x;   // 4*4096
    int layer = idx >> 12, jj = idx & 4095;
    int u = jj >> 2, g = jj & 3;
    int src_j = (g << 10) + u;
    const float* pi; const float* ph;
    switch (layer) {
        case 0:  pi = e0i; ph = e0h; break;
        case 1:  pi = e1i; ph = e1h; break;
        case 2:  pi = d0i; ph = d0h; break;
        default: pi = d1i; ph = d1h; break;
    }
    out[idx] = pi[src_j] + ph[src_j];
}

// ---------------- merged fused LSTM step ----------------
struct StepArgs {
    const unsigned short* Wh;   // seg0 weights [4096][1024] gate-interleaved bf16
    const unsigned short* Sh;   // seg0 state   [2048][1024] bf16 batch-major
    const unsigned short* Wx;   // seg1 weights [4096][Kx] gate-interleaved
    const unsigned short* Sx;   // seg1 state (or bemb [37][Kx] with tok)
    int Kx;                     // seg1 K
    const int* tok;             // [2048] gather rows of Sx, or null
    const float4* b4;           // [1024] per-unit (i,f,g,o) bias
    unsigned short* c;          // [2048][1024] fp16 batch-major
    unsigned short* hout;       // [2048][1024] bf16
    int valid;
};

#define GRS 132   // Gs row stride (col-major [64][132] fp32)

// grid (96, 16): x = z*32+m -> linear_id % 8 == m % 8 (XCD weight locality)
// z=0 -> s0 (layer1 step d), z=1 -> s1 (layer0 step d+1), z=2 -> FC of h1(d-1)
__global__ __launch_bounds__(256, 4)
void lstm_fused(StepArgs s0, StepArgs s1,
                const unsigned short* __restrict__ fch, int fct,
                const unsigned short* __restrict__ fcW, const float* __restrict__ fcb,
                float* __restrict__ out) {
    const int tid  = threadIdx.x;
    const int lane = tid & 63;
    const int wave = tid >> 6;
    const int zx = blockIdx.x;          // 0..95
    const int z  = zx >> 5, m = zx & 31;
    const int n  = blockIdx.y;

    if (z == 2) {      // ---- FC slice: logits for previous step's h1 ----
        if (!fch) return;
        const int row = (n * 32 + m) * 4 + wave;    // 0..2047
        if (lane >= VV) return;
        const unsigned short* hrow = fch + (size_t)row * HH;
        const unsigned short* wrow = fcW + (size_t)lane * HH;
        float acc = fcb[lane];
#pragma unroll 4
        for (int k8 = 0; k8 < HH / 8; ++k8) {
            short8 hv = *reinterpret_cast<const short8*>(hrow + k8 * 8);
            short8 wv = *reinterpret_cast<const short8*>(wrow + k8 * 8);
#pragma unroll
            for (int uu = 0; uu < 8; ++uu)
                acc += bf2f((unsigned short)hv[uu]) * bf2f((unsigned short)wv[uu]);
        }
        out[(size_t)row * (SS * VV) + fct * VV + lane] = acc;
        return;
    }

    StepArgs S = (z == 0) ? s0 : s1;
    if (!S.valid) return;

    __shared__ __align__(16) unsigned char smem[64 * GRS * 4];   // 33792 B
    unsigned short* As = (unsigned short*)smem;             // 16 KB staging
    unsigned short* Bs = (unsigned short*)(smem + 16384);   // 16 KB staging
    float* Gs = (float*)smem;                               // epilogue reuse: [64][GRS]

    const int wm = wave >> 1, wn = wave & 1;
    const int m0 = m * 128;    // gate-row base
    const int n0 = n * 128;    // batch base

    floatx4 acc[4][4];
#pragma unroll
    for (int i = 0; i < 4; ++i)
#pragma unroll
        for (int j = 0; j < 4; ++j)
            acc[i][j] = (floatx4){0.f, 0.f, 0.f, 0.f};

    const int r16  = lane & 15;
    const int koff = (lane >> 4) << 3;
    const int t0 = wave, t1 = wave + 4;

#pragma unroll 1
    for (int seg = 0; seg < 2; ++seg) {
        const unsigned short* A = seg ? S.Wx : S.Wh;
        const unsigned short* B = seg ? S.Sx : S.Sh;
        if (!A) break;
        const int K = seg ? S.Kx : HH;
        const bool gather = seg && (S.tok != nullptr);
        const size_t a0 = (size_t)(m0 + t0 * 16 + r16) * K + koff;
        const size_t a1 = (size_t)(m0 + t1 * 16 + r16) * K + koff;
        size_t b0, b1;
        if (gather) {
            b0 = (size_t)S.tok[n0 + t0 * 16 + r16] * K + koff;
            b1 = (size_t)S.tok[n0 + t1 * 16 + r16] * K + koff;
        } else {
            b0 = (size_t)(n0 + t0 * 16 + r16) * K + koff;
            b1 = (size_t)(n0 + t1 * 16 + r16) * K + koff;
        }
        for (int kc = 0; kc < K; kc += 64) {
            gl_lds16(A + a0 + kc,      As + ((t0 * 2 + 0) << 9));
            gl_lds16(A + a0 + kc + 32, As + ((t0 * 2 + 1) << 9));
            gl_lds16(A + a1 + kc,      As + ((t1 * 2 + 0) << 9));
            gl_lds16(A + a1 + kc + 32, As + ((t1 * 2 + 1) << 9));
            gl_lds16(B + b0 + kc,      Bs + ((t0 * 2 + 0) << 9));
            gl_lds16(B + b0 + kc + 32, Bs + ((t0 * 2 + 1) << 9));
            gl_lds16(B + b1 + kc,      Bs + ((t1 * 2 + 0) << 9));
            gl_lds16(B + b1 + kc + 32, Bs + ((t1 * 2 + 1) << 9));
            __syncthreads();
#pragma unroll
            for (int h = 0; h < 2; ++h) {
                short8 af[4], bfr[4];
#pragma unroll
                for (int i = 0; i < 4; ++i) {
                    af[i]  = *reinterpret_cast<const short8*>(As + ((((wm * 4 + i) * 2 + h) << 9) + (lane << 3)));
                    bfr[i] = *reinterpret_cast<const short8*>(Bs + ((((wn * 4 + i) * 2 + h) << 9) + (lane << 3)));
                }
#pragma unroll
                for (int i = 0; i < 4; ++i)
#pragma unroll
                    for (int j = 0; j < 4; ++j)
                        acc[i][j] = __builtin_amdgcn_mfma_f32_16x16x32_bf16(af[i], bfr[j], acc[i][j], 0, 0, 0);
            }
            __syncthreads();
        }
    }

    // ---- two-pass epilogue through Gs (col-major [gatecol 64][batch GRS]) ----
    // C/D layout: gate-col = wm*64 + i*16 + q*4 + p, batch-col = wn*64 + j*16 + r  [m89]
    const int q = lane >> 4, r = lane & 15;
    const int u    = tid & 15;        // unit within pass
    const int rgrp = tid >> 4;        // 16 groups x 8 batch rows
#pragma unroll
    for (int gp = 0; gp < 2; ++gp) {
        if (wm == gp) {
            // lanes r=0..15 write stride-1 (2-way bank alias only)
#pragma unroll
            for (int i = 0; i < 4; ++i)
#pragma unroll
                for (int p = 0; p < 4; ++p)
#pragma unroll
                    for (int j = 0; j < 4; ++j)
                        Gs[(i * 16 + q * 4 + p) * GRS + (wn * 64 + j * 16 + r)] = acc[i][j][p];
        }
        __syncthreads();
        const int unit = (m0 >> 2) + gp * 16 + u;
        const float4 bv = S.b4[unit];
#pragma unroll
        for (int rr = 0; rr < 8; ++rr) {
            const int row = rgrp * 8 + rr;                  // batch-local 0..127
            float gx = Gs[(u * 4 + 0) * GRS + row] + bv.x;
            float gy = Gs[(u * 4 + 1) * GRS + row] + bv.y;
            float gz = Gs[(u * 4 + 2) * GRS + row] + bv.z;
            float gw = Gs[(u * 4 + 3) * GRS + row] + bv.w;
            float iv = sigm(gx), fv = sigm(gy), gv = tanh_(gz), ov = sigm(gw);
            const size_t ci = (size_t)(n0 + row) * HH + unit;
            float cn = fv * h2f(S.c[ci]) + iv * gv;
            S.c[ci] = f2h(cn);
            S.hout[ci] = f2bf(ov * tanh_(cn));
        }
        __syncthreads();
    }
}

// standalone FC for the final timestep
__global__ __launch_bounds__(256)
void fc_step_kernel(const unsigned short* __restrict__ h1, const unsigned short* __restrict__ fcW,
                    const float* __restrict__ fcb, float* __restrict__ out, int t) {
    int b    = (blockIdx.x * 256 + threadIdx.x) >> 6;
    int lane = threadIdx.x & 63;
    if (lane >= VV) return;
    const unsigned short* hrow = h1 + (size_t)b * HH;
    const unsigned short* wrow = fcW + (size_t)lane * HH;
    float acc = fcb[lane];
#pragma unroll 4
    for (int k8 = 0; k8 < HH / 8; ++k8) {
        short8 hv = *reinterpret_cast<const short8*>(hrow + k8 * 8);
        short8 wv = *reinterpret_cast<const short8*>(wrow + k8 * 8);
#pragma unroll
        for (int uu = 0; uu < 8; ++uu)
            acc += bf2f((unsigned short)hv[uu]) * bf2f((unsigned short)wv[uu]);
    }
    out[(size_t)b * (SS * VV) + t * VV + lane] = acc;
}

extern "C" void kernel_launch(void* const* d_in, const int* in_sizes, int n_in,
                              void* d_out, int out_size, void* d_ws, size_t ws_size,
                              hipStream_t stream) {
    const int*   src    = (const int*)d_in[0];
    const int*   tgt    = (const int*)d_in[1];
    const float* emb    = (const float*)d_in[2];
    const float* eW_ih0 = (const float*)d_in[3];
    const float* eW_hh0 = (const float*)d_in[4];
    const float* eb_ih0 = (const float*)d_in[5];
    const float* eb_hh0 = (const float*)d_in[6];
    const float* eW_ih1 = (const float*)d_in[7];
    const float* eW_hh1 = (const float*)d_in[8];
    const float* eb_ih1 = (const float*)d_in[9];
    const float* eb_hh1 = (const float*)d_in[10];
    const float* dW_ih0 = (const float*)d_in[11];
    const float* dW_hh0 = (const float*)d_in[12];
    const float* db_ih0 = (const float*)d_in[13];
    const float* db_hh0 = (const float*)d_in[14];
    const float* dW_ih1 = (const float*)d_in[15];
    const float* dW_hh1 = (const float*)d_in[16];
    const float* db_ih1 = (const float*)d_in[17];
    const float* db_hh1 = (const float*)d_in[18];
    const float* fcW    = (const float*)d_in[19];
    const float* fcb    = (const float*)d_in[20];
    float* out = (float*)d_out;

    // ---- workspace ----
    char* w = (char*)d_ws;
    size_t off = 0;
    auto walloc = [&](size_t bytes) { void* p = w + off; off += (bytes + 255) & ~(size_t)255; return p; };
    // gate-interleaved bf16 weights: 6 big (K=1024) + 2 small (K=256)
    unsigned short* bW[8];
    const float* srcW[8] = {eW_hh0, eW_ih1, eW_hh1, dW_hh0, dW_ih1, dW_hh1, eW_ih0, dW_ih0};
    const int     szW[8] = {G4H*HH, G4H*HH, G4H*HH, G4H*HH, G4H*HH, G4H*HH, G4H*EE, G4H*EE};
    for (int i = 0; i < 8; ++i) bW[i] = (unsigned short*)walloc((size_t)szW[i] * 2);
    unsigned short* bfcW = (unsigned short*)walloc((size_t)VV * HH * 2);
    unsigned short* bemb = (unsigned short*)walloc((size_t)VV * EE * 2);
    // zero region: h0a, h1a (bf16) + c0, c1 (fp16) — contiguous 16 MiB
    unsigned short* h0a = (unsigned short*)walloc((size_t)BB * HH * 2);
    unsigned short* h1a = (unsigned short*)walloc((size_t)BB * HH * 2);
    unsigned short* c0 = (unsigned short*)walloc((size_t)BB * HH * 2);
    unsigned short* c1 = (unsigned short*)walloc((size_t)BB * HH * 2);
    unsigned short* h0b = (unsigned short*)walloc((size_t)BB * HH * 2);
    unsigned short* h1b = (unsigned short*)walloc((size_t)BB * HH * 2);
    float* bsum = (float*)walloc((size_t)4 * G4H * 4);
    int*   toks = (int*)walloc((size_t)2 * SS * BB * 4);

    unsigned short* h0buf[2] = {h0a, h0b};
    unsigned short* h1buf[2] = {h1a, h1b};
    const float4* b4 = (const float4*)bsum;   // [4 layers][1024 units]

    // ---- setup ----
    for (int i = 0; i < 8; ++i) {
        int kqshift = (szW[i] == G4H * EE) ? 6 : 8;
        cvt_perm_kernel<<<szW[i] / 4 / 256, 256, 0, stream>>>(srcW[i], bW[i], kqshift);
    }
    cvt_f2b_kernel<<<(VV * HH / 4 + 255) / 256, 256, 0, stream>>>(fcW, bfcW, VV * HH / 4);
    cvt_f2b_kernel<<<(VV * EE / 4 + 255) / 256, 256, 0, stream>>>(emb, bemb, VV * EE / 4);
    zero16_kernel<<<4096, 256, 0, stream>>>((uint4*)h0a);   // 16 MiB
    bias_sum_kernel<<<64, 256, 0, stream>>>(eb_ih0, eb_hh0, eb_ih1, eb_hh1,
                                            db_ih0, db_hh0, db_ih1, db_hh1, bsum);
    tok_kernel<<<384, 256, 0, stream>>>(src, tgt, toks);

    StepArgs nil; nil.Wh = nullptr; nil.Sh = nullptr; nil.Wx = nullptr; nil.Sx = nullptr;
    nil.Kx = 0; nil.tok = nullptr; nil.b4 = nullptr; nil.c = nullptr; nil.hout = nullptr; nil.valid = 0;

    dim3 grid(96, 16);

    // ---- prologue: layer0 step 0 only ----
    {
        StepArgs p1 = { bW[0], h0buf[0], bW[6], bemb, EE, toks, b4 + 0 * 1024, c0, h0buf[1], 1 };
        lstm_fused<<<grid, 256, 0, stream>>>(nil, p1, nullptr, 0, bfcW, fcb, out);
    }

    // ---- main: dispatch d = layer1 step d + layer0 step d+1 + FC of step d-1 ----
    for (int d = 0; d < 48; ++d) {
        const unsigned short* h0cur = h0buf[1 ^ (d & 1)];
        unsigned short*       h0nxt = h0buf[d & 1];
        const unsigned short* h1in  = h1buf[d & 1];
        unsigned short*       h1out = h1buf[1 ^ (d & 1)];
        const bool l1enc = d < SS;
        const bool l0enc = (d + 1) < SS;

        StepArgs s0 = { l1enc ? bW[2] : bW[5], h1in, l1enc ? bW[1] : bW[4], h0cur,
                        HH, nullptr, l1enc ? (b4 + 1 * 1024) : (b4 + 3 * 1024), c1, h1out, 1 };
        StepArgs s1 = nil;
        if (d < 47) {
            s1.Wh = l0enc ? bW[0] : bW[3]; s1.Sh = h0cur;
            s1.Wx = l0enc ? bW[6] : bW[7]; s1.Sx = bemb; s1.Kx = EE;
            s1.tok = toks + (size_t)(d + 1) * BB;
            s1.b4 = l0enc ? (b4 + 0 * 1024) : (b4 + 2 * 1024);
            s1.c = c0; s1.hout = h0nxt; s1.valid = 1;
        }
        const unsigned short* fch = (d >= 25) ? h1buf[1 ^ ((d - 1) & 1)] : nullptr;
        lstm_fused<<<grid, 256, 0, stream>>>(s0, s1, fch, d - 25, bfcW, fcb, out);
    }
    // final FC: t = 23 from h1 of dispatch d=47 (h1out = h1buf[0])
    fc_step_kernel<<<512, 256, 0, stream>>>(h1buf[0], bfcW, fcb, out, 23);
}